// Round 11
// baseline (967.925 us; speedup 1.0000x reference)
//
#include <hip/hip_runtime.h>
#include <hip/hip_fp16.h>

#define HIDDIM 256
#define NHEADS 8
#define SCORE_SHIFT 4.0f

struct __attribute__((aligned(8)))  half4s { __half2 a, b; };
struct __attribute__((aligned(16))) half8s { __half2 a, b, c, d; };

typedef _Float16 f16x8 __attribute__((ext_vector_type(8)));
typedef float f32x4 __attribute__((ext_vector_type(4)));

// ---------------- converts ----------------
__global__ __launch_bounds__(256) void cvt_f2h(
    const float* __restrict__ in, __half* __restrict__ out, int n) {
  const int i = blockIdx.x * 256 + threadIdx.x;
  if (i < n) out[i] = __float2half(in[i]);
}

// in [K][N] fp32 -> out [N][K] fp16 (transposed)
__global__ __launch_bounds__(256) void cvt_transpose(
    const float* __restrict__ in, __half* __restrict__ out, int K, int N) {
  const int idx = blockIdx.x * 256 + threadIdx.x;
  if (idx >= K * N) return;
  const int n = idx / K, k = idx - n * K;
  out[idx] = __float2half(in[(size_t)k * N + n]);
}

// ---------------- MFMA GEMM: C16[M,N] = act(A16[M,K] @ Wt16[N,K]^T + bias) ----------------
template <int RELU>
__global__ __launch_bounds__(256) void gemm_mfma(
    const _Float16* __restrict__ A, const _Float16* __restrict__ Wt,
    const float* __restrict__ bias, _Float16* __restrict__ C,
    int M, int N, int K) {
  const int wv = threadIdx.x >> 6;
  const int lane = threadIdx.x & 63;
  const int bn = blockIdx.x * 64;
  const int bm = blockIdx.y * 64 + wv * 16;
  const int fr = lane & 15;
  const int kb = lane >> 4;

  int arow = bm + fr; if (arow >= M) arow = M - 1;
  const _Float16* ap = A + (size_t)arow * K + kb * 8;
  const _Float16* bp = Wt + (size_t)(bn + fr) * K + kb * 8;

  f32x4 acc[4] = {};
  for (int k0 = 0; k0 < K; k0 += 32) {
    const f16x8 a = *(const f16x8*)(ap + k0);
    #pragma unroll
    for (int nt = 0; nt < 4; ++nt) {
      const f16x8 b = *(const f16x8*)(bp + (size_t)nt * 16 * K + k0);
      acc[nt] = __builtin_amdgcn_mfma_f32_16x16x32_f16(a, b, acc[nt], 0, 0, 0);
    }
  }
  #pragma unroll
  for (int r = 0; r < 4; ++r) {
    const int row = bm + (lane >> 4) * 4 + r;
    if (row >= M) continue;
    #pragma unroll
    for (int nt = 0; nt < 4; ++nt) {
      const int col = bn + nt * 16 + fr;
      float v = acc[nt][r] + bias[col];
      if (RELU && v < 0.f) v = 0.f;
      C[(size_t)row * N + col] = (_Float16)v;
    }
  }
}

// ---------------- CSR build (by destination; stores SRC node id) ----------------
__global__ __launch_bounds__(256) void count_deg(
    const int* __restrict__ ei, int* __restrict__ deg, int E, int Nn) {
  const int t = blockIdx.x * blockDim.x + threadIdx.x;
  const int ET = E + Nn;
  if (t >= ET) return;
  const int dst = (t < E) ? ei[E + t] : (t - E);
  atomicAdd(&deg[dst], 1);
}

__global__ __launch_bounds__(1024) void scan_deg(
    const int* __restrict__ deg, int* __restrict__ rowptr, int Nn) {
  __shared__ int wsum[16];
  __shared__ int carry_s;
  const int tid = threadIdx.x;
  const int wid = tid >> 6, lane = tid & 63;
  if (tid == 0) { carry_s = 0; rowptr[0] = 0; }
  __syncthreads();
  for (int base = 0; base < Nn; base += 1024) {
    const int i = base + tid;
    int s = (i < Nn) ? deg[i] : 0;
    #pragma unroll
    for (int off = 1; off < 64; off <<= 1) {
      int t = __shfl_up(s, off);
      if (lane >= off) s += t;
    }
    if (lane == 63) wsum[wid] = s;
    __syncthreads();
    if (wid == 0 && lane < 16) {
      int ws = wsum[lane];
      #pragma unroll
      for (int off = 1; off < 16; off <<= 1) {
        int t = __shfl_up(ws, off);
        if (lane >= off) ws += t;
      }
      wsum[lane] = ws;
    }
    __syncthreads();
    const int prefix = (wid > 0 ? wsum[wid - 1] : 0) + carry_s;
    if (i < Nn) rowptr[i + 1] = s + prefix;
    __syncthreads();
    if (tid == 0) carry_s += wsum[15];
    __syncthreads();
  }
}

__global__ __launch_bounds__(256) void fill_csr(
    const int* __restrict__ ei, const int* __restrict__ rowptr,
    int* __restrict__ cursor, int* __restrict__ csr, int E, int Nn) {
  const int t = blockIdx.x * blockDim.x + threadIdx.x;
  const int ET = E + Nn;
  if (t >= ET) return;
  int src, dst;
  if (t < E) { src = ei[t]; dst = ei[E + t]; }
  else { src = t - E; dst = t - E; }
  const int pos = atomicAdd(&cursor[dst], 1);
  csr[rowptr[dst] + pos] = src;
}

// ---------------- fused GATv2 per-node, PAIRED gathers ----------------
// wave per node; half = lane>>5 owns edge j+half; lane owns 8 channels (16B fp16).
// one VMEM instruction fetches TWO full xl rows (32 lanes x 16B each).
// max-free softmax: w = exp(s - SHIFT); tail masked by s=-inf -> w=0.
template <int MODE>
__global__ __launch_bounds__(256) void node_gat(
    const __half* __restrict__ xl, const __half* __restrict__ xr,
    const int* __restrict__ rowptr, const int* __restrict__ csr,
    const float* __restrict__ att, const float* __restrict__ bias,
    const float* __restrict__ lng, const float* __restrict__ lnb,
    const int* __restrict__ batch, float* __restrict__ pooled,
    float* __restrict__ counts, __half* __restrict__ outp, int Nn) {
  int n = (int)((blockIdx.x * (size_t)blockDim.x + threadIdx.x) >> 6);
  const int lane = threadIdx.x & 63;
  if (n >= Nn) return;
  n = __builtin_amdgcn_readfirstlane(n);
  const int r0 = rowptr[n], r1 = rowptr[n + 1];
  const int half = lane >> 5, l5 = lane & 31;

  float xrv[8], atv[8];
  {
    const half8s xh = *((const half8s*)(xr + (size_t)n * HIDDIM) + l5);
    float2 f;
    f = __half22float2(xh.a); xrv[0] = f.x; xrv[1] = f.y;
    f = __half22float2(xh.b); xrv[2] = f.x; xrv[3] = f.y;
    f = __half22float2(xh.c); xrv[4] = f.x; xrv[5] = f.y;
    f = __half22float2(xh.d); xrv[6] = f.x; xrv[7] = f.y;
    const float4 a0 = *(const float4*)(att + l5 * 8);
    const float4 a1 = *(const float4*)(att + l5 * 8 + 4);
    atv[0] = a0.x; atv[1] = a0.y; atv[2] = a0.z; atv[3] = a0.w;
    atv[4] = a1.x; atv[5] = a1.y; atv[6] = a1.z; atv[7] = a1.w;
  }

  float acc[8] = {};
  float den = 0.f;

  for (int j = r0; j < r1; j += 2) {
    const int jj = j + half;
    const bool valid = jj < r1;
    const int src = csr[valid ? jj : j];
    const half8s ah = *((const half8s*)(xl + (size_t)src * HIDDIM) + l5);
    float a[8];
    {
      float2 f;
      f = __half22float2(ah.a); a[0] = f.x; a[1] = f.y;
      f = __half22float2(ah.b); a[2] = f.x; a[3] = f.y;
      f = __half22float2(ah.c); a[4] = f.x; a[5] = f.y;
      f = __half22float2(ah.d); a[6] = f.x; a[7] = f.y;
    }
    float s = 0.f;
    #pragma unroll
    for (int k = 0; k < 8; ++k) {
      float v = a[k] + xrv[k];
      v = v >= 0.f ? v : 0.2f * v;
      s = fmaf(v, atv[k], s);
    }
    s += __shfl_xor(s, 1);
    s += __shfl_xor(s, 2);          // full 32-ch head dot (4-lane group)
    if (!valid) s = -1e30f;
    const float w = __expf(s - SCORE_SHIFT);
    #pragma unroll
    for (int k = 0; k < 8; ++k) acc[k] = fmaf(w, a[k], acc[k]);
    den += w;
  }

  // merge the two halves
  #pragma unroll
  for (int k = 0; k < 8; ++k) acc[k] += __shfl_xor(acc[k], 32);
  den += __shfl_xor(den, 32);
  const float inv_d = 1.f / den;

  float bv[8];
  {
    const float4 b0 = *(const float4*)(bias + l5 * 8);
    const float4 b1 = *(const float4*)(bias + l5 * 8 + 4);
    bv[0] = b0.x; bv[1] = b0.y; bv[2] = b0.z; bv[3] = b0.w;
    bv[4] = b1.x; bv[5] = b1.y; bv[6] = b1.z; bv[7] = b1.w;
  }
  float t[8];
  #pragma unroll
  for (int k = 0; k < 8; ++k) {
    t[k] = fmaf(acc[k], inv_d, bv[k]);
    t[k] = t[k] > 0.f ? t[k] : 0.f;
  }

  if (MODE == 0) {
    float s = 0.f;
    #pragma unroll
    for (int k = 0; k < 8; ++k) s += t[k];
    #pragma unroll
    for (int mm = 1; mm < 32; mm <<= 1) s += __shfl_xor(s, mm);   // within-half = full 256 ch
    const float mu = s * (1.f / HIDDIM);
    float q = 0.f;
    float dv[8];
    #pragma unroll
    for (int k = 0; k < 8; ++k) { dv[k] = t[k] - mu; q += dv[k] * dv[k]; }
    #pragma unroll
    for (int mm = 1; mm < 32; mm <<= 1) q += __shfl_xor(q, mm);
    const float inv = rsqrtf(q * (1.f / HIDDIM) + 1e-5f);
    if (half == 0) {
      const float4 g0 = *(const float4*)(lng + l5 * 8);
      const float4 g1 = *(const float4*)(lng + l5 * 8 + 4);
      const float4 p0 = *(const float4*)(lnb + l5 * 8);
      const float4 p1 = *(const float4*)(lnb + l5 * 8 + 4);
      const float gv[8] = {g0.x, g0.y, g0.z, g0.w, g1.x, g1.y, g1.z, g1.w};
      const float pv[8] = {p0.x, p0.y, p0.z, p0.w, p1.x, p1.y, p1.z, p1.w};
      half8s ho;
      ho.a = __floats2half2_rn(dv[0] * inv * gv[0] + pv[0], dv[1] * inv * gv[1] + pv[1]);
      ho.b = __floats2half2_rn(dv[2] * inv * gv[2] + pv[2], dv[3] * inv * gv[3] + pv[3]);
      ho.c = __floats2half2_rn(dv[4] * inv * gv[4] + pv[4], dv[5] * inv * gv[5] + pv[5]);
      ho.d = __floats2half2_rn(dv[6] * inv * gv[6] + pv[6], dv[7] * inv * gv[7] + pv[7]);
      *((half8s*)(outp + (size_t)n * HIDDIM) + l5) = ho;
    }
  } else {
    if (half == 0) {
      const int g = batch[n];
      float* p = pooled + (size_t)g * HIDDIM + l5 * 8;
      #pragma unroll
      for (int k = 0; k < 8; ++k) atomicAdd(p + k, t[k]);
      if (lane == 0) atomicAdd(&counts[g], 1.f);
    }
  }
}

// ---------------- head MLP ----------------
__global__ __launch_bounds__(256) void head_kernel(
    const float* __restrict__ pooled, const float* __restrict__ counts,
    const float* __restrict__ h1w, const float* __restrict__ h1b,
    const float* __restrict__ h2w, const float* __restrict__ h2b,
    float* __restrict__ out, int G, int H1, int OUT) {
  __shared__ float P[16][HIDDIM];
  __shared__ float Hh[16][128];
  const int tid = threadIdx.x;
  for (int i = tid; i < G * HIDDIM; i += 256) {
    const int g = i / HIDDIM, c = i % HIDDIM;
    float cnt = counts[g];
    if (cnt < 1.f) cnt = 1.f;
    P[g][c] = pooled[i] / cnt;
  }
  __syncthreads();
  for (int i = tid; i < G * H1; i += 256) {
    const int g = i / H1, j = i % H1;
    float s = h1b[j];
    for (int k = 0; k < HIDDIM; ++k) s = fmaf(P[g][k], h1w[k * H1 + j], s);
    Hh[g][j] = s > 0.f ? s : 0.f;
  }
  __syncthreads();
  for (int i = tid; i < G * OUT; i += 256) {
    const int g = i / OUT, o = i % OUT;
    float s = h2b[o];
    for (int k = 0; k < H1; ++k) s = fmaf(Hh[g][k], h2w[k * OUT + o], s);
    out[i] = s;
  }
}

extern "C" void kernel_launch(void* const* d_in, const int* in_sizes, int n_in,
                              void* d_out, int out_size, void* d_ws, size_t ws_size,
                              hipStream_t stream) {
  const float* x = (const float*)d_in[0];
  const int* ei = (const int*)d_in[1];
  const int* batch = (const int*)d_in[2];
  const float* enc_w = (const float*)d_in[3];
  const float* enc_b = (const float*)d_in[4];
  const float* g_wl[2] = {(const float*)d_in[5], (const float*)d_in[11]};
  const float* g_bl[2] = {(const float*)d_in[6], (const float*)d_in[12]};
  const float* g_wr[2] = {(const float*)d_in[7], (const float*)d_in[13]};
  const float* g_br[2] = {(const float*)d_in[8], (const float*)d_in[14]};
  const float* g_att[2] = {(const float*)d_in[9], (const float*)d_in[15]};
  const float* g_bias[2] = {(const float*)d_in[10], (const float*)d_in[16]};
  const float* ln_g = (const float*)d_in[17];
  const float* ln_b = (const float*)d_in[18];
  const float* h1_w = (const float*)d_in[19];
  const float* h1_b = (const float*)d_in[20];
  const float* h2_w = (const float*)d_in[21];
  const float* h2_b = (const float*)d_in[22];
  float* out = (float*)d_out;

  const int N = in_sizes[2];          // 20000
  const int E = in_sizes[1] / 2;      // 320000
  const int DIN = in_sizes[0] / N;    // 128
  const int ET = E + N;
  const int H1 = in_sizes[20];        // 128
  const int OUT = in_sizes[22];       // 2
  const int G = out_size / OUT;       // 16

  char* base = (char*)d_ws;
  const size_t NH = (size_t)N * HIDDIM;
  __half* h16  = (__half*)base;                    // [N][256]
  __half* xl16 = h16 + NH;
  __half* xr16 = xl16 + NH;
  __half* x16  = xr16 + NH;                        // [N][DIN]
  __half* wtE  = x16 + (size_t)N * DIN;            // [256][DIN]
  __half* wt[4];
  wt[0] = wtE + (size_t)HIDDIM * DIN;
  wt[1] = wt[0] + (size_t)HIDDIM * HIDDIM;
  wt[2] = wt[1] + (size_t)HIDDIM * HIDDIM;
  wt[3] = wt[2] + (size_t)HIDDIM * HIDDIM;
  float* pooled = (float*)(wt[3] + (size_t)HIDDIM * HIDDIM);
  float* counts = pooled + (size_t)G * HIDDIM;
  int* deg    = (int*)(counts + G);
  int* rowptr = deg + N;
  int* cursor = rowptr + (N + 1);
  int* csr    = cursor + N;

  const dim3 blk(256);
  const int eb = (ET + 255) / 256;
  const int nb = (N + 3) / 4;
  const dim3 mfma_grid(HIDDIM / 64, (N + 63) / 64);

  // CSR build (graph identical for both layers)
  hipMemsetAsync(deg, 0, (size_t)N * sizeof(int), stream);
  hipMemsetAsync(cursor, 0, (size_t)N * sizeof(int), stream);
  hipMemsetAsync(pooled, 0, ((size_t)G * HIDDIM + G) * sizeof(float), stream);
  count_deg<<<eb, blk, 0, stream>>>(ei, deg, E, N);
  scan_deg<<<1, 1024, 0, stream>>>(deg, rowptr, N);
  fill_csr<<<eb, blk, 0, stream>>>(ei, rowptr, cursor, csr, E, N);

  // weight/input conversion
  cvt_f2h<<<(N * DIN + 255) / 256, blk, 0, stream>>>(x, x16, N * DIN);
  cvt_transpose<<<(DIN * HIDDIM + 255) / 256, blk, 0, stream>>>(enc_w, wtE, DIN, HIDDIM);
  cvt_transpose<<<(HIDDIM * HIDDIM + 255) / 256, blk, 0, stream>>>(g_wl[0], wt[0], HIDDIM, HIDDIM);
  cvt_transpose<<<(HIDDIM * HIDDIM + 255) / 256, blk, 0, stream>>>(g_wr[0], wt[1], HIDDIM, HIDDIM);
  cvt_transpose<<<(HIDDIM * HIDDIM + 255) / 256, blk, 0, stream>>>(g_wl[1], wt[2], HIDDIM, HIDDIM);
  cvt_transpose<<<(HIDDIM * HIDDIM + 255) / 256, blk, 0, stream>>>(g_wr[1], wt[3], HIDDIM, HIDDIM);

  // encoder: h16 = relu(x @ enc_w + enc_b)
  gemm_mfma<1><<<mfma_grid, blk, 0, stream>>>(
      (const _Float16*)x16, (const _Float16*)wtE, enc_b, (_Float16*)h16, N, HIDDIM, DIN);

  for (int L = 0; L < 2; ++L) {
    gemm_mfma<0><<<mfma_grid, blk, 0, stream>>>(
        (const _Float16*)h16, (const _Float16*)wt[2 * L + 0], g_bl[L], (_Float16*)xl16, N, HIDDIM, HIDDIM);
    gemm_mfma<0><<<mfma_grid, blk, 0, stream>>>(
        (const _Float16*)h16, (const _Float16*)wt[2 * L + 1], g_br[L], (_Float16*)xr16, N, HIDDIM, HIDDIM);
    if (L == 0) {
      node_gat<0><<<nb, blk, 0, stream>>>(xl16, xr16, rowptr, csr, g_att[0], g_bias[0],
                                          ln_g, ln_b, nullptr, nullptr, nullptr, h16, N);
    } else {
      node_gat<1><<<nb, blk, 0, stream>>>(xl16, xr16, rowptr, csr, g_att[1], g_bias[1],
                                          nullptr, nullptr, batch, pooled, counts, nullptr, N);
    }
  }
  head_kernel<<<1, blk, 0, stream>>>(pooled, counts, h1_w, h1_b, h2_w, h2_b, out, G, H1, OUT);
}

// Round 12
// 697.515 us; speedup vs baseline: 1.3877x; 1.3877x over previous
//
#include <hip/hip_runtime.h>
#include <hip/hip_fp16.h>

#define HIDDIM 256
#define NHEADS 8
#define SCORE_SHIFT 4.0f

struct __attribute__((aligned(8)))  half4s { __half2 a, b; };
struct __attribute__((aligned(16))) half8s { __half2 a, b, c, d; };

typedef _Float16 f16x8 __attribute__((ext_vector_type(8)));
typedef float f32x4 __attribute__((ext_vector_type(4)));

// ---------------- converts ----------------
__global__ __launch_bounds__(256) void cvt_f2h(
    const float* __restrict__ in, __half* __restrict__ out, int n) {
  const int i = blockIdx.x * 256 + threadIdx.x;
  if (i < n) out[i] = __float2half(in[i]);
}

// in [K][N] fp32 -> out [N][K] fp16 (transposed)
__global__ __launch_bounds__(256) void cvt_transpose(
    const float* __restrict__ in, __half* __restrict__ out, int K, int N) {
  const int idx = blockIdx.x * 256 + threadIdx.x;
  if (idx >= K * N) return;
  const int n = idx / K, k = idx - n * K;
  out[idx] = __float2half(in[(size_t)k * N + n]);
}

// ---------------- MFMA GEMM: C16[M,N] = act(A16[M,K] @ Wt16[N,K]^T + bias) ----------------
template <int RELU>
__global__ __launch_bounds__(256) void gemm_mfma(
    const _Float16* __restrict__ A, const _Float16* __restrict__ Wt,
    const float* __restrict__ bias, _Float16* __restrict__ C,
    int M, int N, int K) {
  const int wv = threadIdx.x >> 6;
  const int lane = threadIdx.x & 63;
  const int bn = blockIdx.x * 64;
  const int bm = blockIdx.y * 64 + wv * 16;
  const int fr = lane & 15;
  const int kb = lane >> 4;

  int arow = bm + fr; if (arow >= M) arow = M - 1;
  const _Float16* ap = A + (size_t)arow * K + kb * 8;
  const _Float16* bp = Wt + (size_t)(bn + fr) * K + kb * 8;

  f32x4 acc[4] = {};
  for (int k0 = 0; k0 < K; k0 += 32) {
    const f16x8 a = *(const f16x8*)(ap + k0);
    #pragma unroll
    for (int nt = 0; nt < 4; ++nt) {
      const f16x8 b = *(const f16x8*)(bp + (size_t)nt * 16 * K + k0);
      acc[nt] = __builtin_amdgcn_mfma_f32_16x16x32_f16(a, b, acc[nt], 0, 0, 0);
    }
  }
  #pragma unroll
  for (int r = 0; r < 4; ++r) {
    const int row = bm + (lane >> 4) * 4 + r;
    if (row >= M) continue;
    #pragma unroll
    for (int nt = 0; nt < 4; ++nt) {
      const int col = bn + nt * 16 + fr;
      float v = acc[nt][r] + bias[col];
      if (RELU && v < 0.f) v = 0.f;
      C[(size_t)row * N + col] = (_Float16)v;
    }
  }
}

// ---------------- CSR build (by destination; stores SRC and DST per slot) ----------------
__global__ __launch_bounds__(256) void count_deg(
    const int* __restrict__ ei, int* __restrict__ deg, int E, int Nn) {
  const int t = blockIdx.x * blockDim.x + threadIdx.x;
  const int ET = E + Nn;
  if (t >= ET) return;
  const int dst = (t < E) ? ei[E + t] : (t - E);
  atomicAdd(&deg[dst], 1);
}

__global__ __launch_bounds__(1024) void scan_deg(
    const int* __restrict__ deg, int* __restrict__ rowptr, int Nn) {
  __shared__ int wsum[16];
  __shared__ int carry_s;
  const int tid = threadIdx.x;
  const int wid = tid >> 6, lane = tid & 63;
  if (tid == 0) { carry_s = 0; rowptr[0] = 0; }
  __syncthreads();
  for (int base = 0; base < Nn; base += 1024) {
    const int i = base + tid;
    int s = (i < Nn) ? deg[i] : 0;
    #pragma unroll
    for (int off = 1; off < 64; off <<= 1) {
      int t = __shfl_up(s, off);
      if (lane >= off) s += t;
    }
    if (lane == 63) wsum[wid] = s;
    __syncthreads();
    if (wid == 0 && lane < 16) {
      int ws = wsum[lane];
      #pragma unroll
      for (int off = 1; off < 16; off <<= 1) {
        int t = __shfl_up(ws, off);
        if (lane >= off) ws += t;
      }
      wsum[lane] = ws;
    }
    __syncthreads();
    const int prefix = (wid > 0 ? wsum[wid - 1] : 0) + carry_s;
    if (i < Nn) rowptr[i + 1] = s + prefix;
    __syncthreads();
    if (tid == 0) carry_s += wsum[15];
    __syncthreads();
  }
}

__global__ __launch_bounds__(256) void fill_csr(
    const int* __restrict__ ei, const int* __restrict__ rowptr,
    int* __restrict__ cursor, int* __restrict__ csr, int* __restrict__ csrd,
    int E, int Nn) {
  const int t = blockIdx.x * blockDim.x + threadIdx.x;
  const int ET = E + Nn;
  if (t >= ET) return;
  int src, dst;
  if (t < E) { src = ei[t]; dst = ei[E + t]; }
  else { src = t - E; dst = t - E; }
  const int pos = atomicAdd(&cursor[dst], 1);
  csr[rowptr[dst] + pos] = src;
  csrd[rowptr[dst] + pos] = dst;
}

// ---------------- edge_w: flat edge-parallel score kernel (2 edges/wave) ----------------
// CSR slot j: gather xl[src], xr[dst] (16B/lane, one fp16 row per 32-lane half);
// w = exp(score - SHIFT); write wq[j][h] fp32 (11 MB, cache-resident).
__global__ __launch_bounds__(256) void edge_w(
    const __half* __restrict__ xl, const __half* __restrict__ xr,
    const int* __restrict__ csr, const int* __restrict__ csrd,
    const float* __restrict__ att, float* __restrict__ wq, int ET) {
  const int wave = (int)((blockIdx.x * (size_t)blockDim.x + threadIdx.x) >> 6);
  const int lane = threadIdx.x & 63;
  if (wave * 2 >= ET) return;
  int j = wave * 2 + (lane >> 5);
  if (j >= ET) j = ET - 1;                 // duplicate write, same value: benign
  const int l5 = lane & 31;
  const int src = csr[j];
  const int dst = csrd[j];

  const half8s ha = *((const half8s*)(xl + (size_t)src * HIDDIM) + l5);
  const half8s hb = *((const half8s*)(xr + (size_t)dst * HIDDIM) + l5);
  const float4 at0 = *((const float4*)(att + l5 * 8));
  const float4 at1 = *((const float4*)(att + l5 * 8 + 4));

  float a[8], b[8];
  {
    float2 f;
    f = __half22float2(ha.a); a[0] = f.x; a[1] = f.y;
    f = __half22float2(ha.b); a[2] = f.x; a[3] = f.y;
    f = __half22float2(ha.c); a[4] = f.x; a[5] = f.y;
    f = __half22float2(ha.d); a[6] = f.x; a[7] = f.y;
    f = __half22float2(hb.a); b[0] = f.x; b[1] = f.y;
    f = __half22float2(hb.b); b[2] = f.x; b[3] = f.y;
    f = __half22float2(hb.c); b[4] = f.x; b[5] = f.y;
    f = __half22float2(hb.d); b[6] = f.x; b[7] = f.y;
  }
  const float atv[8] = {at0.x, at0.y, at0.z, at0.w, at1.x, at1.y, at1.z, at1.w};
  float s = 0.f;
  #pragma unroll
  for (int k = 0; k < 8; ++k) {
    float v = a[k] + b[k];
    v = v >= 0.f ? v : 0.2f * v;
    s = fmaf(v, atv[k], s);
  }
  s += __shfl_xor(s, 1);
  s += __shfl_xor(s, 2);                   // 4-lane group = one 32-ch head
  if ((l5 & 3) == 0) wq[(size_t)j * NHEADS + (l5 >> 2)] = __expf(s - SCORE_SHIFT);
}

// ---------------- node_agg: lean per-node aggregation (no shuffles, no xr) ----------------
// wave per node; lane owns channels [4*lane,4*lane+4); head h = lane>>3.
// 8-wide: 8 row-loads + 8 scalar w-loads per iteration; chain = cvt+fma only.
template <int MODE>
__global__ __launch_bounds__(256) void node_agg(
    const __half* __restrict__ xl, const float* __restrict__ wq,
    const int* __restrict__ rowptr, const int* __restrict__ csr,
    const float* __restrict__ bias, const float* __restrict__ lng,
    const float* __restrict__ lnb, const int* __restrict__ batch,
    float* __restrict__ pooled, float* __restrict__ counts,
    __half* __restrict__ outp, int Nn) {
  int n = (int)((blockIdx.x * (size_t)blockDim.x + threadIdx.x) >> 6);
  const int lane = threadIdx.x & 63;
  if (n >= Nn) return;
  n = __builtin_amdgcn_readfirstlane(n);
  const int r0 = rowptr[n], r1 = rowptr[n + 1];
  const int jm = r1 - 1;
  const int h = lane >> 3;
  const half4s* __restrict__ xlv = (const half4s*)xl;

  float4 acc = make_float4(0.f, 0.f, 0.f, 0.f);
  float den = 0.f;

  for (int j0 = r0; j0 <= jm; j0 += 8) {
    half4s r[8];
    float w[8];
    #pragma unroll
    for (int k = 0; k < 8; ++k) {
      int j = j0 + k; j = j <= jm ? j : jm;
      r[k] = xlv[(size_t)csr[j] * (HIDDIM / 4) + lane];
      w[k] = wq[(size_t)j * NHEADS + h];
    }
    #pragma unroll
    for (int k = 0; k < 8; ++k) if (j0 + k > jm) w[k] = 0.f;
    #pragma unroll
    for (int k = 0; k < 8; ++k) {
      const float2 f01 = __half22float2(r[k].a);
      const float2 f23 = __half22float2(r[k].b);
      acc.x = fmaf(w[k], f01.x, acc.x);
      acc.y = fmaf(w[k], f01.y, acc.y);
      acc.z = fmaf(w[k], f23.x, acc.z);
      acc.w = fmaf(w[k], f23.y, acc.w);
      den += w[k];
    }
  }
  const float inv_d = 1.f / den;

  const float4 bb = *(const float4*)(bias + lane * 4);
  float t0 = fmaf(acc.x, inv_d, bb.x); t0 = t0 > 0.f ? t0 : 0.f;
  float t1 = fmaf(acc.y, inv_d, bb.y); t1 = t1 > 0.f ? t1 : 0.f;
  float t2 = fmaf(acc.z, inv_d, bb.z); t2 = t2 > 0.f ? t2 : 0.f;
  float t3 = fmaf(acc.w, inv_d, bb.w); t3 = t3 > 0.f ? t3 : 0.f;

  if (MODE == 0) {
    float s = t0 + t1 + t2 + t3;
    #pragma unroll
    for (int mm = 1; mm < 64; mm <<= 1) s += __shfl_xor(s, mm);
    const float mu = s * (1.f / HIDDIM);
    const float d0 = t0 - mu, d1 = t1 - mu, d2 = t2 - mu, d3 = t3 - mu;
    float q = d0 * d0 + d1 * d1 + d2 * d2 + d3 * d3;
    #pragma unroll
    for (int mm = 1; mm < 64; mm <<= 1) q += __shfl_xor(q, mm);
    const float inv = rsqrtf(q * (1.f / HIDDIM) + 1e-5f);
    const float4 g4 = *(const float4*)(lng + lane * 4);
    const float4 b4 = *(const float4*)(lnb + lane * 4);
    half4s ho;
    ho.a = __floats2half2_rn(d0 * inv * g4.x + b4.x, d1 * inv * g4.y + b4.y);
    ho.b = __floats2half2_rn(d2 * inv * g4.z + b4.z, d3 * inv * g4.w + b4.w);
    *((half4s*)outp + (size_t)n * (HIDDIM / 4) + lane) = ho;
  } else {
    const int g = batch[n];
    float* p = pooled + (size_t)g * HIDDIM + lane * 4;
    atomicAdd(p + 0, t0);
    atomicAdd(p + 1, t1);
    atomicAdd(p + 2, t2);
    atomicAdd(p + 3, t3);
    if (lane == 0) atomicAdd(&counts[g], 1.f);
  }
}

// ---------------- head MLP ----------------
__global__ __launch_bounds__(256) void head_kernel(
    const float* __restrict__ pooled, const float* __restrict__ counts,
    const float* __restrict__ h1w, const float* __restrict__ h1b,
    const float* __restrict__ h2w, const float* __restrict__ h2b,
    float* __restrict__ out, int G, int H1, int OUT) {
  __shared__ float P[16][HIDDIM];
  __shared__ float Hh[16][128];
  const int tid = threadIdx.x;
  for (int i = tid; i < G * HIDDIM; i += 256) {
    const int g = i / HIDDIM, c = i % HIDDIM;
    float cnt = counts[g];
    if (cnt < 1.f) cnt = 1.f;
    P[g][c] = pooled[i] / cnt;
  }
  __syncthreads();
  for (int i = tid; i < G * H1; i += 256) {
    const int g = i / H1, j = i % H1;
    float s = h1b[j];
    for (int k = 0; k < HIDDIM; ++k) s = fmaf(P[g][k], h1w[k * H1 + j], s);
    Hh[g][j] = s > 0.f ? s : 0.f;
  }
  __syncthreads();
  for (int i = tid; i < G * OUT; i += 256) {
    const int g = i / OUT, o = i % OUT;
    float s = h2b[o];
    for (int k = 0; k < H1; ++k) s = fmaf(Hh[g][k], h2w[k * OUT + o], s);
    out[i] = s;
  }
}

extern "C" void kernel_launch(void* const* d_in, const int* in_sizes, int n_in,
                              void* d_out, int out_size, void* d_ws, size_t ws_size,
                              hipStream_t stream) {
  const float* x = (const float*)d_in[0];
  const int* ei = (const int*)d_in[1];
  const int* batch = (const int*)d_in[2];
  const float* enc_w = (const float*)d_in[3];
  const float* enc_b = (const float*)d_in[4];
  const float* g_wl[2] = {(const float*)d_in[5], (const float*)d_in[11]};
  const float* g_bl[2] = {(const float*)d_in[6], (const float*)d_in[12]};
  const float* g_wr[2] = {(const float*)d_in[7], (const float*)d_in[13]};
  const float* g_br[2] = {(const float*)d_in[8], (const float*)d_in[14]};
  const float* g_att[2] = {(const float*)d_in[9], (const float*)d_in[15]};
  const float* g_bias[2] = {(const float*)d_in[10], (const float*)d_in[16]};
  const float* ln_g = (const float*)d_in[17];
  const float* ln_b = (const float*)d_in[18];
  const float* h1_w = (const float*)d_in[19];
  const float* h1_b = (const float*)d_in[20];
  const float* h2_w = (const float*)d_in[21];
  const float* h2_b = (const float*)d_in[22];
  float* out = (float*)d_out;

  const int N = in_sizes[2];          // 20000
  const int E = in_sizes[1] / 2;      // 320000
  const int DIN = in_sizes[0] / N;    // 128
  const int ET = E + N;
  const int H1 = in_sizes[20];        // 128
  const int OUT = in_sizes[22];       // 2
  const int G = out_size / OUT;       // 16

  char* base = (char*)d_ws;
  const size_t NH = (size_t)N * HIDDIM;
  __half* h16  = (__half*)base;                    // [N][256]
  __half* xl16 = h16 + NH;
  __half* xr16 = xl16 + NH;
  __half* x16  = xr16 + NH;                        // [N][DIN]
  __half* wtE  = x16 + (size_t)N * DIN;            // [256][DIN]
  __half* wt[4];
  wt[0] = wtE + (size_t)HIDDIM * DIN;
  wt[1] = wt[0] + (size_t)HIDDIM * HIDDIM;
  wt[2] = wt[1] + (size_t)HIDDIM * HIDDIM;
  wt[3] = wt[2] + (size_t)HIDDIM * HIDDIM;
  float* wq    = (float*)(wt[3] + (size_t)HIDDIM * HIDDIM);  // [ET][8] f32
  float* pooled = wq + (size_t)ET * NHEADS;
  float* counts = pooled + (size_t)G * HIDDIM;
  int* deg    = (int*)(counts + G);
  int* rowptr = deg + N;
  int* cursor = rowptr + (N + 1);
  int* csr    = cursor + N;
  int* csrd   = csr + ET;

  const dim3 blk(256);
  const int eb = (ET + 255) / 256;
  const int nb = (N + 3) / 4;
  const int wb = (int)(((size_t)(ET + 1) / 2 + 3) / 4);
  const dim3 mfma_grid(HIDDIM / 64, (N + 63) / 64);

  // CSR build (graph identical for both layers)
  hipMemsetAsync(deg, 0, (size_t)N * sizeof(int), stream);
  hipMemsetAsync(cursor, 0, (size_t)N * sizeof(int), stream);
  hipMemsetAsync(pooled, 0, ((size_t)G * HIDDIM + G) * sizeof(float), stream);
  count_deg<<<eb, blk, 0, stream>>>(ei, deg, E, N);
  scan_deg<<<1, 1024, 0, stream>>>(deg, rowptr, N);
  fill_csr<<<eb, blk, 0, stream>>>(ei, rowptr, cursor, csr, csrd, E, N);

  // weight/input conversion
  cvt_f2h<<<(N * DIN + 255) / 256, blk, 0, stream>>>(x, x16, N * DIN);
  cvt_transpose<<<(DIN * HIDDIM + 255) / 256, blk, 0, stream>>>(enc_w, wtE, DIN, HIDDIM);
  cvt_transpose<<<(HIDDIM * HIDDIM + 255) / 256, blk, 0, stream>>>(g_wl[0], wt[0], HIDDIM, HIDDIM);
  cvt_transpose<<<(HIDDIM * HIDDIM + 255) / 256, blk, 0, stream>>>(g_wr[0], wt[1], HIDDIM, HIDDIM);
  cvt_transpose<<<(HIDDIM * HIDDIM + 255) / 256, blk, 0, stream>>>(g_wl[1], wt[2], HIDDIM, HIDDIM);
  cvt_transpose<<<(HIDDIM * HIDDIM + 255) / 256, blk, 0, stream>>>(g_wr[1], wt[3], HIDDIM, HIDDIM);

  // encoder: h16 = relu(x @ enc_w + enc_b)
  gemm_mfma<1><<<mfma_grid, blk, 0, stream>>>(
      (const _Float16*)x16, (const _Float16*)wtE, enc_b, (_Float16*)h16, N, HIDDIM, DIN);

  for (int L = 0; L < 2; ++L) {
    gemm_mfma<0><<<mfma_grid, blk, 0, stream>>>(
        (const _Float16*)h16, (const _Float16*)wt[2 * L + 0], g_bl[L], (_Float16*)xl16, N, HIDDIM, HIDDIM);
    gemm_mfma<0><<<mfma_grid, blk, 0, stream>>>(
        (const _Float16*)h16, (const _Float16*)wt[2 * L + 1], g_br[L], (_Float16*)xr16, N, HIDDIM, HIDDIM);
    edge_w<<<wb, blk, 0, stream>>>(xl16, xr16, csr, csrd, g_att[L], wq, ET);
    if (L == 0) {
      node_agg<0><<<nb, blk, 0, stream>>>(xl16, wq, rowptr, csr, g_bias[0],
                                          ln_g, ln_b, nullptr, nullptr, nullptr, h16, N);
    } else {
      node_agg<1><<<nb, blk, 0, stream>>>(xl16, wq, rowptr, csr, g_bias[1],
                                          nullptr, nullptr, batch, pooled, counts, nullptr, N);
    }
  }
  head_kernel<<<1, blk, 0, stream>>>(pooled, counts, h1_w, h1_b, h2_w, h2_b, out, G, H1, OUT);
}